// Round 1
// baseline (1135.627 us; speedup 1.0000x reference)
//
#include <hip/hip_runtime.h>

#define N_NODES 100000
#define N_EDGES 3200000
#define DIM 512
#define MPAD 100096      // 782*128
#define MTILES 782
#define BN_EPS 1e-5f

typedef _Float16 half8 __attribute__((ext_vector_type(8)));
typedef float floatx4 __attribute__((ext_vector_type(4)));

// ---------------- conversion kernels ----------------

__global__ __launch_bounds__(256) void convert_x_kernel(const float* __restrict__ x,
                                                        _Float16* __restrict__ out) {
    size_t idx = ((size_t)blockIdx.x * 256 + threadIdx.x) * 8;
    int row = (int)(idx >> 9);
    half8 h;
    if (row < N_NODES) {
        const float4* p = (const float4*)(x + idx);
        float4 a = p[0], b = p[1];
        h[0] = (_Float16)a.x; h[1] = (_Float16)a.y; h[2] = (_Float16)a.z; h[3] = (_Float16)a.w;
        h[4] = (_Float16)b.x; h[5] = (_Float16)b.y; h[6] = (_Float16)b.z; h[7] = (_Float16)b.w;
    } else {
        #pragma unroll
        for (int k = 0; k < 8; ++k) h[k] = (_Float16)0.0f;
    }
    *(half8*)(out + idx) = h;
}

__global__ __launch_bounds__(256) void convert_w_kernel(const float* __restrict__ in,
                                                        _Float16* __restrict__ out) {
    size_t idx = ((size_t)blockIdx.x * 256 + threadIdx.x) * 8;  // < 262144
    const float4* p = (const float4*)(in + idx);
    float4 a = p[0], b = p[1];
    half8 h;
    h[0] = (_Float16)a.x; h[1] = (_Float16)a.y; h[2] = (_Float16)a.z; h[3] = (_Float16)a.w;
    h[4] = (_Float16)b.x; h[5] = (_Float16)b.y; h[6] = (_Float16)b.z; h[7] = (_Float16)b.w;
    *(half8*)(out + idx) = h;
}

// ---------------- graph scale kernels ----------------

__global__ __launch_bounds__(256) void deg_kernel(const int* __restrict__ ei,
                                                  float* __restrict__ degf) {
    int e = blockIdx.x * 256 + threadIdx.x;
    if (e < N_EDGES) {
        int s = ei[e], d = ei[N_EDGES + e];
        if (s != d) atomicAdd(&degf[d], 1.0f);
    }
}

__global__ __launch_bounds__(256) void node_scale_init(const float* __restrict__ degf,
                                                       float* __restrict__ dinv,
                                                       float* __restrict__ sarr) {
    int i = blockIdx.x * 256 + threadIdx.x;
    if (i < MPAD) {
        if (i < N_NODES) {
            float d = degf[i] + 1.0f;   // +1 self loop
            dinv[i] = rsqrtf(d);
            sarr[i] = 1.0f / d;          // self-loop term of s
        } else {
            dinv[i] = 0.f;
            sarr[i] = 0.f;
        }
    }
}

__global__ __launch_bounds__(256) void scatter_s_kernel(const int* __restrict__ ei,
                                                        const float* __restrict__ dinv,
                                                        float* __restrict__ sarr) {
    int e = blockIdx.x * 256 + threadIdx.x;
    if (e < N_EDGES) {
        int s = ei[e], d = ei[N_EDGES + e];
        if (s != d) atomicAdd(&sarr[s], dinv[s] * dinv[d]);
    }
}

// ---------------- GEMM: C[m,n] = (sum_k A[m,k]*W[n,k]) * s[m] + bias[n] ----------------
// 128x128 tile, BK=32, 4 waves in 2x2 (each 64x64 via 4x4 of 16x16x32 MFMA).
// !FINAL: store f16, accumulate column sum/sumsq (rows < N_NODES only).
// FINAL:  store f32 to d_out, rows < N_NODES only.

template <bool FINAL>
__global__ __launch_bounds__(256) void gemm_kernel(
    const _Float16* __restrict__ A,     // [MPAD][512]
    const _Float16* __restrict__ W,     // [512][512] (row = output channel)
    const float* __restrict__ sarr,     // [MPAD]
    const float* __restrict__ bias,     // [512]
    void* __restrict__ out,
    float* __restrict__ colsum,
    float* __restrict__ colsq)
{
    __shared__ _Float16 As[128 * 32];
    __shared__ _Float16 Bs[128 * 32];
    __shared__ float lsum[128];
    __shared__ float lsq[128];

    const int tid  = threadIdx.x;
    const int wave = tid >> 6;
    const int lane = tid & 63;
    const int quad = lane >> 4;
    const int l16  = lane & 15;

    const int ct = blockIdx.x & 3;   // 4 column tiles (512/128)
    const int rt = blockIdx.x >> 2;  // 782 row tiles
    const int m0 = rt * 128;
    const int n0 = ct * 128;
    const int wm = (wave >> 1) * 64;
    const int wn = (wave & 1) * 64;

    floatx4 acc[4][4];
    #pragma unroll
    for (int i = 0; i < 4; ++i)
        #pragma unroll
        for (int j = 0; j < 4; ++j)
            acc[i][j] = (floatx4){0.f, 0.f, 0.f, 0.f};

    // staging geometry: tile is row-major [128][32] f16 (64 B/row), 8 KB.
    // 256 threads x 16 B = 4 KB per issue; 2 issues. LDS dst must be
    // wave-uniform base + lane*16 -> flat byte offset f0 below.
    const int f0 = wave * 1024 + lane * 16;  // 0..4080
    const int ra = f0 >> 6;                  // row within 64-row half
    const int ca = f0 & 63;                  // byte col within row

    const char* Ab = (const char*)(A + (size_t)m0 * DIM) + ca;
    const char* Bb = (const char*)(W + (size_t)n0 * DIM) + ca;

    for (int kb = 0; kb < DIM; kb += 32) {
        #pragma unroll
        for (int is = 0; is < 2; ++is) {
            int r = is * 64 + ra;
            __builtin_amdgcn_global_load_lds(
                (const __attribute__((address_space(1))) void*)(Ab + (size_t)r * (DIM * 2) + kb * 2),
                (__attribute__((address_space(3))) void*)(As + is * 2048 + (f0 >> 1)),
                16, 0, 0);
            __builtin_amdgcn_global_load_lds(
                (const __attribute__((address_space(1))) void*)(Bb + (size_t)r * (DIM * 2) + kb * 2),
                (__attribute__((address_space(3))) void*)(Bs + is * 2048 + (f0 >> 1)),
                16, 0, 0);
        }
        __syncthreads();

        half8 af[4], bfr[4];
        #pragma unroll
        for (int i = 0; i < 4; ++i)
            af[i] = *(const half8*)(As + (wm + i * 16 + l16) * 32 + quad * 8);
        #pragma unroll
        for (int j = 0; j < 4; ++j)
            bfr[j] = *(const half8*)(Bs + (wn + j * 16 + l16) * 32 + quad * 8);

        #pragma unroll
        for (int i = 0; i < 4; ++i)
            #pragma unroll
            for (int j = 0; j < 4; ++j)
                acc[i][j] = __builtin_amdgcn_mfma_f32_16x16x32_f16(af[i], bfr[j], acc[i][j], 0, 0, 0);

        __syncthreads();
    }

    // epilogue
    if (!FINAL) {
        if (tid < 128) { lsum[tid] = 0.f; lsq[tid] = 0.f; }
        __syncthreads();
    }

    float4 sva[4];
    #pragma unroll
    for (int i = 0; i < 4; ++i)
        sva[i] = *(const float4*)(sarr + m0 + wm + i * 16 + quad * 4);
    float bv[4];
    #pragma unroll
    for (int j = 0; j < 4; ++j)
        bv[j] = bias[n0 + wn + j * 16 + l16];

    #pragma unroll
    for (int j = 0; j < 4; ++j) {
        const int col_g = n0 + wn + j * 16 + l16;
        float cs = 0.f, cq = 0.f;
        #pragma unroll
        for (int i = 0; i < 4; ++i) {
            const int rbase = m0 + wm + i * 16 + quad * 4;
            #pragma unroll
            for (int r = 0; r < 4; ++r) {
                const int row_g = rbase + r;
                const float sval = ((const float*)&sva[i])[r];
                const float yv = acc[i][j][r] * sval + bv[j];
                if (FINAL) {
                    if (row_g < N_NODES)
                        ((float*)out)[(size_t)row_g * DIM + col_g] = yv;
                } else {
                    ((_Float16*)out)[(size_t)row_g * DIM + col_g] = (_Float16)yv;
                    if (row_g < N_NODES) { cs += yv; cq += yv * yv; }
                }
            }
        }
        if (!FINAL) {
            atomicAdd(&lsum[wn + j * 16 + l16], cs);
            atomicAdd(&lsq[wn + j * 16 + l16], cq);
        }
    }
    if (!FINAL) {
        __syncthreads();
        if (tid < 128) {
            atomicAdd(&colsum[n0 + tid], lsum[tid]);
            atomicAdd(&colsq[n0 + tid], lsq[tid]);
        }
    }
}

// ---------------- batchnorm ----------------

__global__ void bn_finalize(const float* __restrict__ colsum, const float* __restrict__ colsq,
                            float* __restrict__ mu, float* __restrict__ rstd) {
    int c = threadIdx.x;  // 512 threads
    float m = colsum[c] * (1.0f / (float)N_NODES);
    float v = colsq[c] * (1.0f / (float)N_NODES) - m * m;
    mu[c] = m;
    rstd[c] = rsqrtf(v + BN_EPS);
}

__global__ __launch_bounds__(256) void bn_apply(_Float16* __restrict__ y,
                                                const float* __restrict__ mu,
                                                const float* __restrict__ rstd) {
    size_t idx = ((size_t)blockIdx.x * 256 + threadIdx.x) * 8;
    int row = (int)(idx >> 9);
    int col = (int)(idx & 511);
    half8 h;
    if (row < N_NODES) {
        h = *(const half8*)(y + idx);
        float4 m0 = *(const float4*)(mu + col);
        float4 m1 = *(const float4*)(mu + col + 4);
        float4 r0 = *(const float4*)(rstd + col);
        float4 r1 = *(const float4*)(rstd + col + 4);
        float mus[8] = {m0.x, m0.y, m0.z, m0.w, m1.x, m1.y, m1.z, m1.w};
        float rs[8]  = {r0.x, r0.y, r0.z, r0.w, r1.x, r1.y, r1.z, r1.w};
        #pragma unroll
        for (int k = 0; k < 8; ++k) {
            float v = ((float)h[k] - mus[k]) * rs[k];
            h[k] = (_Float16)fmaxf(v, 0.f);
        }
    } else {
        #pragma unroll
        for (int k = 0; k < 8; ++k) h[k] = (_Float16)0.0f;  // zero pad rows
    }
    *(half8*)(y + idx) = h;
}

// ---------------- launch ----------------

extern "C" void kernel_launch(void* const* d_in, const int* in_sizes, int n_in,
                              void* d_out, int out_size, void* d_ws, size_t ws_size,
                              hipStream_t stream) {
    const float* graph_node = (const float*)d_in[0];
    const int*   edge_index = (const int*)d_in[1];
    const float* W0 = (const float*)d_in[2];
    const float* b0 = (const float*)d_in[3];
    const float* W1 = (const float*)d_in[4];
    const float* b1 = (const float*)d_in[5];
    const float* W2 = (const float*)d_in[6];
    const float* b2 = (const float*)d_in[7];

    char* ws = (char*)d_ws;
    const size_t XB = (size_t)MPAD * DIM * 2;           // one f16 activation buffer
    _Float16* x0  = (_Float16*)ws;                      // XB bytes
    _Float16* wf  = (_Float16*)(ws + XB);               // 3*512*512 f16
    float* degf   = (float*)(ws + XB + 3 * DIM * DIM * 2);
    float* dinv   = degf + MPAD;
    float* sarr   = dinv + MPAD;
    float* stats  = sarr + MPAD;                        // 4096 floats
    float *sum0 = stats,        *sq0 = stats + 512,  *mu0 = stats + 1024, *rstd0 = stats + 1536;
    float *sum1 = stats + 2048, *sq1 = stats + 2560, *mu1 = stats + 3072, *rstd1 = stats + 3584;

    // layer-0/1 intermediate lives in d_out (f16, 102.5 MB < 204.8 MB)
    _Float16* x1 = (_Float16*)d_out;

    hipMemsetAsync(degf, 0, (size_t)MPAD * sizeof(float), stream);
    hipMemsetAsync(stats, 0, 4096 * sizeof(float), stream);

    const int elemBlocks = MPAD * DIM / 8 / 256;        // 25024
    convert_x_kernel<<<elemBlocks, 256, 0, stream>>>(graph_node, x0);
    convert_w_kernel<<<128, 256, 0, stream>>>(W0, wf);
    convert_w_kernel<<<128, 256, 0, stream>>>(W1, wf + 262144);
    convert_w_kernel<<<128, 256, 0, stream>>>(W2, wf + 524288);

    deg_kernel<<<N_EDGES / 256, 256, 0, stream>>>(edge_index, degf);
    node_scale_init<<<(MPAD + 255) / 256, 256, 0, stream>>>(degf, dinv, sarr);
    scatter_s_kernel<<<N_EDGES / 256, 256, 0, stream>>>(edge_index, dinv, sarr);

    // layer 0: x0 -> x1 (d_out region)
    gemm_kernel<false><<<MTILES * 4, 256, 0, stream>>>(x0, wf, sarr, b0, x1, sum0, sq0);
    bn_finalize<<<1, 512, 0, stream>>>(sum0, sq0, mu0, rstd0);
    bn_apply<<<elemBlocks, 256, 0, stream>>>(x1, mu0, rstd0);

    // layer 1: x1 -> x0
    gemm_kernel<false><<<MTILES * 4, 256, 0, stream>>>(x1, wf + 262144, sarr, b1, x0, sum1, sq1);
    bn_finalize<<<1, 512, 0, stream>>>(sum1, sq1, mu1, rstd1);
    bn_apply<<<elemBlocks, 256, 0, stream>>>(x0, mu1, rstd1);

    // layer 2: x0 -> d_out (f32, masked rows < N)
    gemm_kernel<true><<<MTILES * 4, 256, 0, stream>>>(x0, wf + 524288, sarr, b2, d_out,
                                                      nullptr, nullptr);
}

// Round 2
// 946.667 us; speedup vs baseline: 1.1996x; 1.1996x over previous
//
#include <hip/hip_runtime.h>

#define N_NODES 100000
#define N_EDGES 3200000
#define DIM 512
#define MPAD 100096      // 782*128
#define MTILES 782
#define BN_EPS 1e-5f

// histogram privatization geometry
#define RBITS 14
#define NBINS 16384      // 64 KB LDS of float bins
#define NRANGE 8         // 8*16384 = 131072 >= MPAD
#define NBLK 64          // edge-slice blocks per range
#define EDGES_PER_BLK (N_EDGES / NBLK)   // 50000 (divisible by 4)

typedef _Float16 half8 __attribute__((ext_vector_type(8)));
typedef float floatx4 __attribute__((ext_vector_type(4)));

// ---------------- conversion kernels ----------------

__global__ __launch_bounds__(256) void convert_x_kernel(const float* __restrict__ x,
                                                        _Float16* __restrict__ out) {
    size_t idx = ((size_t)blockIdx.x * 256 + threadIdx.x) * 8;
    int row = (int)(idx >> 9);
    half8 h;
    if (row < N_NODES) {
        const float4* p = (const float4*)(x + idx);
        float4 a = p[0], b = p[1];
        h[0] = (_Float16)a.x; h[1] = (_Float16)a.y; h[2] = (_Float16)a.z; h[3] = (_Float16)a.w;
        h[4] = (_Float16)b.x; h[5] = (_Float16)b.y; h[6] = (_Float16)b.z; h[7] = (_Float16)b.w;
    } else {
        #pragma unroll
        for (int k = 0; k < 8; ++k) h[k] = (_Float16)0.0f;
    }
    *(half8*)(out + idx) = h;
}

__global__ __launch_bounds__(256) void convert_w_kernel(const float* __restrict__ in,
                                                        _Float16* __restrict__ out) {
    size_t idx = ((size_t)blockIdx.x * 256 + threadIdx.x) * 8;  // < 262144
    const float4* p = (const float4*)(in + idx);
    float4 a = p[0], b = p[1];
    half8 h;
    h[0] = (_Float16)a.x; h[1] = (_Float16)a.y; h[2] = (_Float16)a.z; h[3] = (_Float16)a.w;
    h[4] = (_Float16)b.x; h[5] = (_Float16)b.y; h[6] = (_Float16)b.z; h[7] = (_Float16)b.w;
    *(half8*)(out + idx) = h;
}

// ---------------- graph scale: privatized LDS histogram ----------------
// deg pass (IS_DEG): bin 1.0f over dst where src!=dst.
// s pass:            bin dinv[dst] over src where src!=dst.
// Each block owns (range r, edge-slice b); consecutive blockIdx covers all 8
// ranges for one slice so the slice stays LLC-hot. Partials are non-atomic;
// stage-2 reduces 64 partials per bin deterministically. Zero global atomics.

template <bool IS_DEG>
__global__ __launch_bounds__(256) void hist_stage1(const int* __restrict__ ei,
                                                   const float* __restrict__ dinv,
                                                   float* __restrict__ part) {
    __shared__ float bins[NBINS];  // 64 KB
    const int tid = threadIdx.x;
    const int r = blockIdx.x & (NRANGE - 1);
    const int b = blockIdx.x >> 3;
    for (int i = tid; i < NBINS; i += 256) bins[i] = 0.f;
    __syncthreads();

    const int e0 = b * EDGES_PER_BLK;
    const int e1 = e0 + EDGES_PER_BLK;
    const int lo = r << RBITS;
    const int hi = lo + NBINS;
    for (int e = e0 + tid * 4; e < e1; e += 256 * 4) {
        int4 sv = *(const int4*)(ei + e);
        int4 dv = *(const int4*)(ei + N_EDGES + e);
        const int ss[4] = {sv.x, sv.y, sv.z, sv.w};
        const int dd[4] = {dv.x, dv.y, dv.z, dv.w};
        #pragma unroll
        for (int k = 0; k < 4; ++k) {
            const int s = ss[k], d = dd[k];
            if (s == d) continue;
            const int key = IS_DEG ? d : s;
            if (key >= lo && key < hi) {
                const float val = IS_DEG ? 1.0f : dinv[d];
                atomicAdd(&bins[key - lo], val);
            }
        }
    }
    __syncthreads();

    float* dst = part + (size_t)blockIdx.x * NBINS;
    for (int i = tid; i < NBINS; i += 256) dst[i] = bins[i];
}

__global__ __launch_bounds__(256) void hist_stage2_deg(const float* __restrict__ part,
                                                       float* __restrict__ dinv,
                                                       float* __restrict__ sarr) {
    const int i = blockIdx.x * 256 + threadIdx.x;
    if (i >= MPAD) return;
    const int r = i >> RBITS, bin = i & (NBINS - 1);
    float h = 0.f;
    #pragma unroll 8
    for (int b = 0; b < NBLK; ++b)
        h += part[(size_t)(b * NRANGE + r) * NBINS + bin];
    if (i < N_NODES) {
        const float deg = h + 1.0f;    // +1 self-loop
        dinv[i] = rsqrtf(deg);
        sarr[i] = 1.0f / deg;          // self-loop term of s
    } else {
        dinv[i] = 0.f;
        sarr[i] = 0.f;
    }
}

__global__ __launch_bounds__(256) void hist_stage2_s(const float* __restrict__ part,
                                                     const float* __restrict__ dinv,
                                                     float* __restrict__ sarr) {
    const int i = blockIdx.x * 256 + threadIdx.x;
    if (i >= MPAD) return;
    const int r = i >> RBITS, bin = i & (NBINS - 1);
    float t = 0.f;
    #pragma unroll 8
    for (int b = 0; b < NBLK; ++b)
        t += part[(size_t)(b * NRANGE + r) * NBINS + bin];
    if (i < N_NODES) sarr[i] += dinv[i] * t;
}

// ---------------- GEMM: C[m,n] = (sum_k A[m,k]*W[n,k]) * s[m] + bias[n] ----------------
// 128x128 tile, BK=32, 4 waves in 2x2 (each 64x64 via 4x4 of 16x16x32 MFMA).
// !FINAL: store f16, accumulate column sum/sumsq (rows < N_NODES only).
// FINAL:  store f32 to d_out, rows < N_NODES only.

template <bool FINAL>
__global__ __launch_bounds__(256) void gemm_kernel(
    const _Float16* __restrict__ A,     // [MPAD][512]
    const _Float16* __restrict__ W,     // [512][512] (row = output channel)
    const float* __restrict__ sarr,     // [MPAD]
    const float* __restrict__ bias,     // [512]
    void* __restrict__ out,
    float* __restrict__ colsum,
    float* __restrict__ colsq)
{
    __shared__ _Float16 As[128 * 32];
    __shared__ _Float16 Bs[128 * 32];
    __shared__ float lsum[128];
    __shared__ float lsq[128];

    const int tid  = threadIdx.x;
    const int wave = tid >> 6;
    const int lane = tid & 63;
    const int quad = lane >> 4;
    const int l16  = lane & 15;

    const int ct = blockIdx.x & 3;   // 4 column tiles (512/128)
    const int rt = blockIdx.x >> 2;  // 782 row tiles
    const int m0 = rt * 128;
    const int n0 = ct * 128;
    const int wm = (wave >> 1) * 64;
    const int wn = (wave & 1) * 64;

    floatx4 acc[4][4];
    #pragma unroll
    for (int i = 0; i < 4; ++i)
        #pragma unroll
        for (int j = 0; j < 4; ++j)
            acc[i][j] = (floatx4){0.f, 0.f, 0.f, 0.f};

    const int f0 = wave * 1024 + lane * 16;  // 0..4080
    const int ra = f0 >> 6;                  // row within 64-row half
    const int ca = f0 & 63;                  // byte col within row

    const char* Ab = (const char*)(A + (size_t)m0 * DIM) + ca;
    const char* Bb = (const char*)(W + (size_t)n0 * DIM) + ca;

    for (int kb = 0; kb < DIM; kb += 32) {
        #pragma unroll
        for (int is = 0; is < 2; ++is) {
            int r = is * 64 + ra;
            __builtin_amdgcn_global_load_lds(
                (const __attribute__((address_space(1))) void*)(Ab + (size_t)r * (DIM * 2) + kb * 2),
                (__attribute__((address_space(3))) void*)(As + is * 2048 + (f0 >> 1)),
                16, 0, 0);
            __builtin_amdgcn_global_load_lds(
                (const __attribute__((address_space(1))) void*)(Bb + (size_t)r * (DIM * 2) + kb * 2),
                (__attribute__((address_space(3))) void*)(Bs + is * 2048 + (f0 >> 1)),
                16, 0, 0);
        }
        __syncthreads();

        half8 af[4], bfr[4];
        #pragma unroll
        for (int i = 0; i < 4; ++i)
            af[i] = *(const half8*)(As + (wm + i * 16 + l16) * 32 + quad * 8);
        #pragma unroll
        for (int j = 0; j < 4; ++j)
            bfr[j] = *(const half8*)(Bs + (wn + j * 16 + l16) * 32 + quad * 8);

        #pragma unroll
        for (int i = 0; i < 4; ++i)
            #pragma unroll
            for (int j = 0; j < 4; ++j)
                acc[i][j] = __builtin_amdgcn_mfma_f32_16x16x32_f16(af[i], bfr[j], acc[i][j], 0, 0, 0);

        __syncthreads();
    }

    // epilogue
    if (!FINAL) {
        if (tid < 128) { lsum[tid] = 0.f; lsq[tid] = 0.f; }
        __syncthreads();
    }

    float4 sva[4];
    #pragma unroll
    for (int i = 0; i < 4; ++i)
        sva[i] = *(const float4*)(sarr + m0 + wm + i * 16 + quad * 4);
    float bv[4];
    #pragma unroll
    for (int j = 0; j < 4; ++j)
        bv[j] = bias[n0 + wn + j * 16 + l16];

    #pragma unroll
    for (int j = 0; j < 4; ++j) {
        const int col_g = n0 + wn + j * 16 + l16;
        float cs = 0.f, cq = 0.f;
        #pragma unroll
        for (int i = 0; i < 4; ++i) {
            const int rbase = m0 + wm + i * 16 + quad * 4;
            #pragma unroll
            for (int r = 0; r < 4; ++r) {
                const int row_g = rbase + r;
                const float sval = ((const float*)&sva[i])[r];
                const float yv = acc[i][j][r] * sval + bv[j];
                if (FINAL) {
                    if (row_g < N_NODES)
                        ((float*)out)[(size_t)row_g * DIM + col_g] = yv;
                } else {
                    ((_Float16*)out)[(size_t)row_g * DIM + col_g] = (_Float16)yv;
                    if (row_g < N_NODES) { cs += yv; cq += yv * yv; }
                }
            }
        }
        if (!FINAL) {
            atomicAdd(&lsum[wn + j * 16 + l16], cs);
            atomicAdd(&lsq[wn + j * 16 + l16], cq);
        }
    }
    if (!FINAL) {
        __syncthreads();
        if (tid < 128) {
            atomicAdd(&colsum[n0 + tid], lsum[tid]);
            atomicAdd(&colsq[n0 + tid], lsq[tid]);
        }
    }
}

// ---------------- batchnorm ----------------

__global__ void bn_finalize(const float* __restrict__ colsum, const float* __restrict__ colsq,
                            float* __restrict__ mu, float* __restrict__ rstd) {
    int c = threadIdx.x;  // 512 threads
    float m = colsum[c] * (1.0f / (float)N_NODES);
    float v = colsq[c] * (1.0f / (float)N_NODES) - m * m;
    mu[c] = m;
    rstd[c] = rsqrtf(v + BN_EPS);
}

__global__ __launch_bounds__(256) void bn_apply(_Float16* __restrict__ y,
                                                const float* __restrict__ mu,
                                                const float* __restrict__ rstd) {
    size_t idx = ((size_t)blockIdx.x * 256 + threadIdx.x) * 8;
    int row = (int)(idx >> 9);
    int col = (int)(idx & 511);
    half8 h;
    if (row < N_NODES) {
        h = *(const half8*)(y + idx);
        float4 m0 = *(const float4*)(mu + col);
        float4 m1 = *(const float4*)(mu + col + 4);
        float4 r0 = *(const float4*)(rstd + col);
        float4 r1 = *(const float4*)(rstd + col + 4);
        float mus[8] = {m0.x, m0.y, m0.z, m0.w, m1.x, m1.y, m1.z, m1.w};
        float rs[8]  = {r0.x, r0.y, r0.z, r0.w, r1.x, r1.y, r1.z, r1.w};
        #pragma unroll
        for (int k = 0; k < 8; ++k) {
            float v = ((float)h[k] - mus[k]) * rs[k];
            h[k] = (_Float16)fmaxf(v, 0.f);
        }
    } else {
        #pragma unroll
        for (int k = 0; k < 8; ++k) h[k] = (_Float16)0.0f;  // zero pad rows
    }
    *(half8*)(y + idx) = h;
}

// ---------------- launch ----------------

extern "C" void kernel_launch(void* const* d_in, const int* in_sizes, int n_in,
                              void* d_out, int out_size, void* d_ws, size_t ws_size,
                              hipStream_t stream) {
    const float* graph_node = (const float*)d_in[0];
    const int*   edge_index = (const int*)d_in[1];
    const float* W0 = (const float*)d_in[2];
    const float* b0 = (const float*)d_in[3];
    const float* W1 = (const float*)d_in[4];
    const float* b1 = (const float*)d_in[5];
    const float* W2 = (const float*)d_in[6];
    const float* b2 = (const float*)d_in[7];

    char* ws = (char*)d_ws;
    const size_t XB = (size_t)MPAD * DIM * 2;           // one f16 activation buffer
    _Float16* x0  = (_Float16*)ws;                      // XB bytes
    _Float16* wf  = (_Float16*)(ws + XB);               // 3*512*512 f16
    float* dinv   = (float*)(ws + XB + 3 * DIM * DIM * 2);
    float* sarr   = dinv + MPAD;
    float* stats  = sarr + MPAD;                        // 4096 floats
    float *sum0 = stats,        *sq0 = stats + 512,  *mu0 = stats + 1024, *rstd0 = stats + 1536;
    float *sum1 = stats + 2048, *sq1 = stats + 2560, *mu1 = stats + 3072, *rstd1 = stats + 3584;

    // layer-0/1 intermediate lives in d_out (f16, 102.5 MB < 204.8 MB)
    _Float16* x1 = (_Float16*)d_out;
    // histogram partials live in the unused upper region of d_out during the
    // graph phase: 512 blocks x 64 KB = 32 MB at offset 110 MiB (output is
    // 204.8 MB; x1 occupies the first 102.5 MB and is written only later).
    float* part = (float*)((char*)d_out + (size_t)110 * 1024 * 1024);

    hipMemsetAsync(stats, 0, 4096 * sizeof(float), stream);

    const int elemBlocks = MPAD * DIM / 8 / 256;        // 25024
    convert_x_kernel<<<elemBlocks, 256, 0, stream>>>(graph_node, x0);
    convert_w_kernel<<<128, 256, 0, stream>>>(W0, wf);
    convert_w_kernel<<<128, 256, 0, stream>>>(W1, wf + 262144);
    convert_w_kernel<<<128, 256, 0, stream>>>(W2, wf + 524288);

    const int statBlocks = (MPAD + 255) / 256;          // 391
    hist_stage1<true><<<NRANGE * NBLK, 256, 0, stream>>>(edge_index, dinv, part);
    hist_stage2_deg<<<statBlocks, 256, 0, stream>>>(part, dinv, sarr);
    hist_stage1<false><<<NRANGE * NBLK, 256, 0, stream>>>(edge_index, dinv, part);
    hist_stage2_s<<<statBlocks, 256, 0, stream>>>(part, dinv, sarr);

    // layer 0: x0 -> x1 (d_out region)
    gemm_kernel<false><<<MTILES * 4, 256, 0, stream>>>(x0, wf, sarr, b0, x1, sum0, sq0);
    bn_finalize<<<1, 512, 0, stream>>>(sum0, sq0, mu0, rstd0);
    bn_apply<<<elemBlocks, 256, 0, stream>>>(x1, mu0, rstd0);

    // layer 1: x1 -> x0
    gemm_kernel<false><<<MTILES * 4, 256, 0, stream>>>(x1, wf + 262144, sarr, b1, x0, sum1, sq1);
    bn_finalize<<<1, 512, 0, stream>>>(sum1, sq1, mu1, rstd1);
    bn_apply<<<elemBlocks, 256, 0, stream>>>(x0, mu1, rstd1);

    // layer 2: x0 -> d_out (f32, masked rows < N)
    gemm_kernel<true><<<MTILES * 4, 256, 0, stream>>>(x0, wf + 524288, sarr, b2, d_out,
                                                      nullptr, nullptr);
}